// Round 4
// baseline (3830.878 us; speedup 1.0000x reference)
//
#include <hip/hip_runtime.h>

typedef unsigned short u16;
typedef unsigned int u32;
typedef __attribute__((ext_vector_type(8))) short bf16x8;
typedef __attribute__((ext_vector_type(4))) float f32x4;

#define MFMA_BF16(a,b,c) __builtin_amdgcn_mfma_f32_16x16x32_bf16((a),(b),(c),0,0,0)

__device__ __forceinline__ u16 f2bf(float f) {
  union { float f; u32 u; } v; v.f = f;
  u32 r = v.u + 0x7FFFu + ((v.u >> 16) & 1u);
  return (u16)(r >> 16);
}
__device__ __forceinline__ float bf2f(u16 h) {
  union { u32 u; float f; } v; v.u = ((u32)h) << 16; return v.f;
}
__device__ __forceinline__ float tanh_fast(float x) {
  float e = __expf(2.0f * x);
  return 1.0f - 2.0f / (e + 1.0f);
}
__device__ __forceinline__ float exp2_fast(float x) {
  float r; asm("v_exp_f32 %0, %1" : "=v"(r) : "v"(x)); return r;
}
__device__ __forceinline__ float rcp_fast(float x) {
  float r; asm("v_rcp_f32 %0, %1" : "=v"(r) : "v"(x)); return r;
}

// ---- coherent (cross-XCD) ld/st: bypass non-coherent per-XCD L2 ------------
__device__ __forceinline__ void issue_lcoh(bf16x8& v, const u16* p) {
  asm volatile("global_load_dwordx4 %0, %1, off sc0 sc1" : "=v"(v) : "v"(p));
}
__device__ __forceinline__ void vm_wait0() {
  asm volatile("s_waitcnt vmcnt(0)" ::: "memory");
  __builtin_amdgcn_sched_barrier(0);
}
__device__ __forceinline__ void scoh_u32(u32* p, u32 v) {
  asm volatile("global_store_dword %0, %1, off sc0 sc1" :: "v"(p), "v"(v) : "memory");
}
__device__ __forceinline__ void scoh_u16(u16* p, u16 v) {
  u32 w = v;
  asm volatile("global_store_short %0, %1, off sc0 sc1" :: "v"(p), "v"(w) : "memory");
}
__device__ __forceinline__ u32 poll_load(const u32* p) {
  u32 v;
  asm volatile("global_load_dword %0, %1, off sc0 sc1\n\ts_waitcnt vmcnt(0)"
               : "=v"(v) : "v"(p) : "memory");
  return v;
}

// Poll P per-producer flag slots (64B apart) until all >= target. Wave 0 polls.
__device__ __forceinline__ void poll_flags(const u32* base, int P, u32 target) {
  if ((threadIdx.x >> 6) == 0) {
    const int lane = threadIdx.x & 63;
    const u32* slot = base + (size_t)(lane < P ? lane : 0) * 16;
    for (;;) {
      u32 v = poll_load(slot);
      if (lane >= P) v = 0xFFFFFFFFu;
      if (__all(v >= target)) break;
    }
  }
  __syncthreads();
  __builtin_amdgcn_sched_barrier(0);
}
// Post own flag after draining coherent data stores.
__device__ __forceinline__ void post_flag(u32* slot, u32 val) {
  asm volatile("s_waitcnt vmcnt(0)" ::: "memory");
  __syncthreads();
  if (threadIdx.x == 0) scoh_u32(slot, val);
}

// ---------------------------------------------------------------------------
// Prep: bf16 conversions, weight concat/re-layout, embedding gather, init
// ---------------------------------------------------------------------------
__global__ void prep_kernel(
    const float* __restrict__ fcw, const float* __restrict__ enc,
    const float* __restrict__ wenc, const float* __restrict__ wdec,
    const float* __restrict__ wih0, const float* __restrict__ whh0,
    const float* __restrict__ wih1, const float* __restrict__ whh1,
    const float* __restrict__ bih0, const float* __restrict__ bhh0,
    const float* __restrict__ bih1, const float* __restrict__ bhh1,
    const float* __restrict__ emb, const int* __restrict__ yin,
    const float* __restrict__ dih,
    u16* __restrict__ fcwb, u16* __restrict__ encb, u16* __restrict__ wencb,
    u16* __restrict__ wdecb, u16* __restrict__ w0cat, u16* __restrict__ w1cat,
    u16* __restrict__ embbt, float* __restrict__ bias0, float* __restrict__ bias1,
    u16* __restrict__ h0st0, u16* __restrict__ h1st0)
{
  const float SCL = 2.8853900817779268f;   // 2*log2(e): tanh-arg prescale
  const long long total = 43845632LL;
  for (long long i = (long long)blockIdx.x * 256 + threadIdx.x; i < total;
       i += (long long)gridDim.x * 256) {
    if (i < 32768000LL) {                    // fc_w bf16, padded to 32000 rows
      int r = (int)(i >> 10), c = (int)(i & 1023);
      fcwb[i] = (r < 31999) ? f2bf(fcw[(long long)r * 1024 + c]) : (u16)0;
    } else if (i < 36962304LL) {             // encoder_outputs bf16
      long long j = i - 32768000LL; encb[j] = f2bf(enc[j]);
    } else if (i < 37486592LL) {             // W_enc bf16, prescaled
      long long j = i - 36962304LL; wencb[j] = f2bf(wenc[j] * SCL);
    } else if (i < 38010880LL) {             // W_dec bf16, prescaled
      long long j = i - 37486592LL; wdecb[j] = f2bf(wdec[j] * SCL);
    } else if (i < 40632320LL) {             // W0cat [1024][2560]: [emb|h0prev|ctx]
      long long j = i - 38010880LL;
      int r = (int)(j / 2560), c = (int)(j % 2560);
      float v;
      if (c < 512)       v = wih0[(long long)r * 1536 + c];
      else if (c < 1536) v = whh0[(long long)r * 1024 + (c - 512)];
      else               v = wih0[(long long)r * 1536 + (c - 1024)];
      w0cat[j] = f2bf(v);
    } else if (i < 42729472LL) {             // W1cat [1024][2048]: [h0|h1prev]
      long long j = i - 40632320LL;
      int r = (int)(j >> 11), c = (int)(j & 2047);
      w1cat[j] = f2bf(c < 1024 ? wih1[(r << 10) + c] : whh1[(r << 10) + (c - 1024)]);
    } else if (i < 43778048LL) {             // embedding gather -> bf16 [2048][512]
      long long j = i - 42729472LL;
      int bt = (int)(j >> 9), c = (int)(j & 511);
      int y = yin[bt];
      embbt[j] = f2bf(emb[(long long)y * 512 + c]);
    } else if (i < 43779072LL) {             // bias0 = b_ih0 + b_hh0
      int j = (int)(i - 43778048LL); bias0[j] = bih0[j] + bhh0[j];
    } else if (i < 43780096LL) {             // bias1
      int j = (int)(i - 43779072LL); bias1[j] = bih1[j] + bhh1[j];
    } else if (i < 43812864LL) {             // h0 init [32][1024] -> buffer 0
      int j = (int)(i - 43780096LL); h0st0[j] = f2bf(dih[j]);
    } else {                                 // h1 init [32][1024] -> buffer 0
      int j = (int)(i - 43812864LL); h1st0[j] = f2bf(dih[32768 + j]);
    }
  }
}

// ---------------------------------------------------------------------------
// Generic 128x128-tile bf16 MFMA GEMM:  C[M][N] = A[M][K] * B[N][K]^T + bias
// ---------------------------------------------------------------------------
__global__ __launch_bounds__(256) void gemm128(
    const u16* __restrict__ A, const u16* __restrict__ Bm,
    const float* __restrict__ bias, float* __restrict__ C,
    int K, int ldc, int Nvalid, int ntN)
{
  __shared__ u16 As[128 * 32];
  __shared__ u16 Bs[128 * 32];
  const int tid = threadIdx.x;
  const int bid = blockIdx.x;
  const int tM = bid / ntN, tN = bid - tM * ntN;
  const int m0 = tM * 128, n0 = tN * 128;
  const int lane = tid & 63, wid = tid >> 6;
  const int wm = wid >> 1, wn = wid & 1;
  const int srow = tid >> 1, scol = (tid & 1) * 16;

  const u16* gA = A + (size_t)(m0 + srow) * K + scol;
  const u16* gB = Bm + (size_t)(n0 + srow) * K + scol;
  u16* sA = &As[srow * 32 + scol];
  u16* sB = &Bs[srow * 32 + scol];

  f32x4 acc[4][4];
#pragma unroll
  for (int i = 0; i < 4; ++i)
#pragma unroll
    for (int j = 0; j < 4; ++j) acc[i][j] = (f32x4){0, 0, 0, 0};

  const int aoff = (wm * 64 + (lane & 15)) * 32 + ((lane >> 4) << 3);
  const int boff = (wn * 64 + (lane & 15)) * 32 + ((lane >> 4) << 3);

  for (int k0 = 0; k0 < K; k0 += 32) {
    bf16x8 va0 = *(const bf16x8*)(gA + k0);
    bf16x8 va1 = *(const bf16x8*)(gA + k0 + 8);
    bf16x8 vb0 = *(const bf16x8*)(gB + k0);
    bf16x8 vb1 = *(const bf16x8*)(gB + k0 + 8);
    __syncthreads();
    *((bf16x8*)sA) = va0;  *((bf16x8*)(sA + 8)) = va1;
    *((bf16x8*)sB) = vb0;  *((bf16x8*)(sB + 8)) = vb1;
    __syncthreads();
    bf16x8 af[4], bfj[4];
#pragma unroll
    for (int i = 0; i < 4; ++i) af[i] = *(const bf16x8*)&As[aoff + i * 512];
#pragma unroll
    for (int j = 0; j < 4; ++j) bfj[j] = *(const bf16x8*)&Bs[boff + j * 512];
#pragma unroll
    for (int i = 0; i < 4; ++i)
#pragma unroll
      for (int j = 0; j < 4; ++j)
        acc[i][j] = MFMA_BF16(af[i], bfj[j], acc[i][j]);
  }

#pragma unroll
  for (int i = 0; i < 4; ++i) {
#pragma unroll
    for (int j = 0; j < 4; ++j) {
      int row = m0 + wm * 64 + i * 16 + ((lane >> 4) << 2);
      int cc = n0 + wn * 64 + j * 16 + (lane & 15);
      if (cc < Nvalid) {
        float bs = bias ? bias[cc] : 0.f;
#pragma unroll
        for (int jj = 0; jj < 4; ++jj)
          C[(size_t)(row + jj) * ldc + cc] = acc[i][j][jj] + bs;
      }
    }
  }
}

// ---------------------------------------------------------------------------
// Persistent recurrence. Grid = 128 x 512, 1 block/CU.
// Roles: [0,32) ATTN (1/batch) | [32,96) H0 (16 cols) | [96,128) H1 (32 cols)
// Chain per step: H1 -> ATTN -> H0 -> H1 (3 handoffs, per-producer flags).
// Constants (Wdec, encproj, encb, emb, weights) via plain L2-cached loads;
// only the recurrent state (h1, ctx, h0) crosses blocks via sc0sc1.
// ---------------------------------------------------------------------------
__global__ __launch_bounds__(512, 1) void decoder_persistent(
    const u16* __restrict__ wdecb, const u16* __restrict__ w0cat,
    const u16* __restrict__ w1cat, const u16* __restrict__ encb,
    const float* __restrict__ encproj, const u16* __restrict__ embbt,
    const float* __restrict__ bias0, const float* __restrict__ bias1,
    const float* __restrict__ vw, const int* __restrict__ msk,
    u16* __restrict__ ctxst, u16* __restrict__ h0st, u16* __restrict__ h1st,
    u16* __restrict__ h1all, float* __restrict__ outattn, u32* flags)
{
  extern __shared__ char smem[];
  const int tid = threadIdx.x;
  const int bid = blockIdx.x;
  const int lane = tid & 63, wid = tid >> 6;

  if (bid < 32) {
    // ================= ATTN: decp + scores + softmax + context ==============
    const int b = bid;
    float* sf = (float*)smem;
    // sf[0..1023] h1 f32 | [1024..1535] decp | [1536..2047] vw
    // [2048..2175] e/att | [2176..2303] mask | [2304..2311] wave sums
    sf[1536 + tid] = vw[tid];
    if (tid < 128) sf[2176 + tid] = (float)msk[b * 128 + tid];
    __syncthreads();
    for (int t = 0; t < 64; ++t) {
      poll_flags(flags + 96 * 16, 32, (u32)t);          // h1(t-1) ready
      if (tid < 128) {
        bf16x8 v;
        issue_lcoh(v, h1st + (size_t)(t & 1) * 32768 + (size_t)b * 1024 + tid * 8);
        vm_wait0();
#pragma unroll
        for (int j = 0; j < 8; ++j) sf[tid * 8 + j] = bf2f((u16)v[j]);
      }
      __syncthreads();
      {   // decp[a] for a = tid (512 cols), Wdec prescaled, from L2
        float acc = 0.f;
        const u16* wr = wdecb + (size_t)tid * 1024;
#pragma unroll 4
        for (int kk = 0; kk < 1024; kk += 8) {
          bf16x8 w = *(const bf16x8*)(wr + kk);
          f32x4 ha = *(const f32x4*)&sf[kk];
          f32x4 hb = *(const f32x4*)&sf[kk + 4];
          acc = fmaf(bf2f((u16)w[0]), ha[0], acc);
          acc = fmaf(bf2f((u16)w[1]), ha[1], acc);
          acc = fmaf(bf2f((u16)w[2]), ha[2], acc);
          acc = fmaf(bf2f((u16)w[3]), ha[3], acc);
          acc = fmaf(bf2f((u16)w[4]), hb[0], acc);
          acc = fmaf(bf2f((u16)w[5]), hb[1], acc);
          acc = fmaf(bf2f((u16)w[6]), hb[2], acc);
          acc = fmaf(bf2f((u16)w[7]), hb[3], acc);
        }
        sf[1024 + tid] = acc;
      }
      __syncthreads();
      {   // scores: thread (s, q): s=tid>>2 handles a-range q*128..+127
        const int s = tid >> 2, q = tid & 3;
        const float* ep = encproj + (size_t)(b * 128 + s) * 512 + q * 128;
        const float* dp = &sf[1024 + q * 128];
        const float* vv = &sf[1536 + q * 128];
        float acc = 0.f;
#pragma unroll 8
        for (int i = 0; i < 128; ++i) {
          float x = ep[i] + dp[i];                       // prescaled by 2*log2e
          acc = fmaf(vv[i], 1.f - 2.f * rcp_fast(exp2_fast(x) + 1.f), acc);
        }
        acc += __shfl_xor(acc, 1);
        acc += __shfl_xor(acc, 2);
        float e = 0.f;
        if (q == 0) {
          e = (sf[2176 + s] != 0.f) ? __expf(acc) : 0.f;
          sf[2048 + s] = e;
        }
        float ee = e;
#pragma unroll
        for (int off = 1; off < 64; off <<= 1) ee += __shfl_xor(ee, off);
        if (lane == 0) sf[2304 + wid] = ee;
      }
      __syncthreads();
      {
        float tot = sf[2304] + sf[2305] + sf[2306] + sf[2307] +
                    sf[2308] + sf[2309] + sf[2310] + sf[2311];
        if (tid < 128) {
          float e = sf[2048 + tid];
          float att = (tot > 0.f) ? e * rcp_fast(tot) : 0.0078125f;
          sf[2048 + tid] = att;
          outattn[(size_t)(b * 64 + t) * 128 + tid] = att;
        }
      }
      __syncthreads();
      {   // context: 2 cols per thread, encb from L2
        float a0 = 0.f, a1 = 0.f;
        const u16* eb = encb + (size_t)b * 131072 + tid * 2;
#pragma unroll 8
        for (int s = 0; s < 128; ++s) {
          u32 w = *(const u32*)(eb + s * 1024);
          float wa = sf[2048 + s];
          a0 = fmaf(wa, bf2f((u16)(w & 0xffffu)), a0);
          a1 = fmaf(wa, bf2f((u16)(w >> 16)), a1);
        }
        u32 pk = (u32)f2bf(a0) | ((u32)f2bf(a1) << 16);
        scoh_u32((u32*)(ctxst + (size_t)(t & 1) * 32768 + (size_t)b * 1024 + tid * 2), pk);
      }
      post_flag(flags + (size_t)bid * 16, (u32)(t + 1));
    }
  } else if (bid < 96) {
    // ================= H0: h0 = tanh([emb|h0prev|ctx] @ W0^T + b0) ==========
    const int h = bid - 32, n0 = h * 16;
    u16* role = (u16*)smem;                    // 16 x 2568 u16 (82176 B)
    float* bias = (float*)(smem + 82176);
    float* scr  = (float*)(smem + 82432);      // 3*128*4 f32
    {
      const int row = tid >> 5, seg = (tid & 31) * 80;
#pragma unroll
      for (int i = 0; i < 10; ++i)
        *(bf16x8*)&role[row * 2568 + seg + i * 8] =
            *(const bf16x8*)&w0cat[(size_t)(n0 + row) * 2560 + seg + i * 8];
      if (tid < 16) bias[tid] = bias0[n0 + tid];
    }
    __syncthreads();
    const int mh = wid & 1, kq = wid >> 1;
    const int lrow = lane & 15, lk = (lane >> 4) << 3;
    const int b = mh * 16 + lrow;
    for (int t = 0; t < 64; ++t) {
      poll_flags(flags, 32, (u32)(t + 1));              // ctx(t) ready
      f32x4 acc = {0, 0, 0, 0};
      if (kq == 0) {            // emb region k 0..511 (plain, constant)
        const u16* src = embbt + (size_t)(b * 64 + t) * 512 + lk;
#pragma unroll
        for (int i = 0; i < 16; ++i) {
          bf16x8 a = *(const bf16x8*)(src + i * 32);
          acc = MFMA_BF16(a, *(const bf16x8*)&role[lrow * 2568 + i * 32 + lk], acc);
        }
      } else if (kq == 1) {     // h0prev k 512..1023
        const u16* src = h0st + (size_t)(t & 1) * 32768 + (size_t)b * 1024 + lk;
        bf16x8 av[16];
#pragma unroll
        for (int i = 0; i < 16; ++i) issue_lcoh(av[i], src + i * 32);
        vm_wait0();
#pragma unroll
        for (int i = 0; i < 16; ++i)
          acc = MFMA_BF16(av[i], *(const bf16x8*)&role[lrow * 2568 + 512 + i * 32 + lk], acc);
      } else if (kq == 2) {     // h0prev k 1024..1535
        const u16* src = h0st + (size_t)(t & 1) * 32768 + (size_t)b * 1024 + 512 + lk;
        bf16x8 av[16];
#pragma unroll
        for (int i = 0; i < 16; ++i) issue_lcoh(av[i], src + i * 32);
        vm_wait0();
#pragma unroll
        for (int i = 0; i < 16; ++i)
          acc = MFMA_BF16(av[i], *(const bf16x8*)&role[lrow * 2568 + 1024 + i * 32 + lk], acc);
      } else {                  // ctx k 1536..2559 (32 slices)
        const u16* src = ctxst + (size_t)(t & 1) * 32768 + (size_t)b * 1024 + lk;
        bf16x8 av[16];
#pragma unroll
        for (int i = 0; i < 16; ++i) issue_lcoh(av[i], src + i * 32);
        vm_wait0();
#pragma unroll
        for (int i = 0; i < 16; ++i)
          acc = MFMA_BF16(av[i], *(const bf16x8*)&role[lrow * 2568 + 1536 + i * 32 + lk], acc);
#pragma unroll
        for (int i = 0; i < 16; ++i) issue_lcoh(av[i], src + 512 + i * 32);
        vm_wait0();
#pragma unroll
        for (int i = 0; i < 16; ++i)
          acc = MFMA_BF16(av[i], *(const bf16x8*)&role[lrow * 2568 + 2048 + i * 32 + lk], acc);
      }
      if (kq != 0) *(f32x4*)&scr[((kq - 1) * 128 + mh * 64 + lane) * 4] = acc;
      __syncthreads();
      if (kq == 0) {
        f32x4 p1 = *(const f32x4*)&scr[(0 * 128 + mh * 64 + lane) * 4];
        f32x4 p2 = *(const f32x4*)&scr[(1 * 128 + mh * 64 + lane) * 4];
        f32x4 p3 = *(const f32x4*)&scr[(2 * 128 + mh * 64 + lane) * 4];
        const int rb = mh * 16 + ((lane >> 4) << 2);
        const int cg = n0 + lrow;
        const float bs = bias[lrow];
        u16* dst = h0st + (size_t)((t + 1) & 1) * 32768;
#pragma unroll
        for (int j = 0; j < 4; ++j) {
          u16 v = f2bf(tanh_fast(acc[j] + p1[j] + p2[j] + p3[j] + bs));
          scoh_u16(dst + (size_t)(rb + j) * 1024 + cg, v);
        }
      }
      post_flag(flags + (size_t)bid * 16, (u32)(t + 1));
    }
  } else {
    // ================= H1: h1 = tanh([h0|h1prev] @ W1^T + b1) ===============
    const int hh = bid - 96, n0 = hh * 32;
    u16* role = (u16*)smem;                    // 32 x 2056 u16 (131584 B)
    float* bias = (float*)(smem + 131584);
    float* scr  = (float*)(smem + 132096);     // 3*128*8 f32
    {
      const int row = tid >> 4, seg = (tid & 15) * 128;
#pragma unroll
      for (int i = 0; i < 16; ++i)
        *(bf16x8*)&role[row * 2056 + seg + i * 8] =
            *(const bf16x8*)&w1cat[(size_t)(n0 + row) * 2048 + seg + i * 8];
      if (tid < 32) bias[tid] = bias1[n0 + tid];
    }
    __syncthreads();
    const int mh = wid & 1, kq = wid >> 1;
    const int lrow = lane & 15, lk = (lane >> 4) << 3;
    const int b = mh * 16 + lrow;
    for (int t = 0; t < 64; ++t) {
      poll_flags(flags + 32 * 16, 64, (u32)(t + 1));    // h0(t) ready
      const u16* src = (kq < 2)
          ? h0st + (size_t)((t + 1) & 1) * 32768 + (size_t)b * 1024 + kq * 512 + lk
          : h1st + (size_t)(t & 1) * 32768 + (size_t)b * 1024 + (kq - 2) * 512 + lk;
      const int kb = kq * 512 + lk;
      bf16x8 av[16];
#pragma unroll
      for (int i = 0; i < 16; ++i) issue_lcoh(av[i], src + i * 32);
      vm_wait0();
      f32x4 ac0 = {0, 0, 0, 0}, ac1 = {0, 0, 0, 0};
#pragma unroll
      for (int i = 0; i < 16; ++i) {
        ac0 = MFMA_BF16(av[i], *(const bf16x8*)&role[lrow * 2056 + kb + i * 32], ac0);
        ac1 = MFMA_BF16(av[i], *(const bf16x8*)&role[(16 + lrow) * 2056 + kb + i * 32], ac1);
      }
      if (kq != 0) {
        *(f32x4*)&scr[((kq - 1) * 128 + mh * 64 + lane) * 8]     = ac0;
        *(f32x4*)&scr[((kq - 1) * 128 + mh * 64 + lane) * 8 + 4] = ac1;
      }
      __syncthreads();
      if (kq == 0) {
#pragma unroll
        for (int p = 0; p < 3; ++p) {
          f32x4 q0 = *(const f32x4*)&scr[(p * 128 + mh * 64 + lane) * 8];
          f32x4 q1 = *(const f32x4*)&scr[(p * 128 + mh * 64 + lane) * 8 + 4];
#pragma unroll
          for (int j = 0; j < 4; ++j) { ac0[j] += q0[j]; ac1[j] += q1[j]; }
        }
        const int rb = mh * 16 + ((lane >> 4) << 2);
        const int c0g = n0 + lrow, c1g = n0 + 16 + lrow;
        const float bs0 = bias[lrow], bs1 = bias[16 + lrow];
        u16* hn = h1st + (size_t)((t + 1) & 1) * 32768;
#pragma unroll
        for (int j = 0; j < 4; ++j) {
          int row = rb + j;
          u16 v0 = f2bf(tanh_fast(ac0[j] + bs0));
          u16 v1 = f2bf(tanh_fast(ac1[j] + bs1));
          scoh_u16(hn + (size_t)row * 1024 + c0g, v0);
          scoh_u16(hn + (size_t)row * 1024 + c1g, v1);
          h1all[(size_t)(row * 64 + t) * 1024 + c0g] = v0;
          h1all[(size_t)(row * 64 + t) * 1024 + c1g] = v1;
        }
      }
      post_flag(flags + (size_t)bid * 16, (u32)(t + 1));
    }
  }
}

// ---------------------------------------------------------------------------
extern "C" void kernel_launch(void* const* d_in, const int* in_sizes, int n_in,
                              void* d_out, int out_size, void* d_ws, size_t ws_size,
                              hipStream_t stream)
{
  const int*   yin  = (const int*)d_in[0];
  const float* enc  = (const float*)d_in[1];
  const float* dih  = (const float*)d_in[2];
  const int*   msk  = (const int*)d_in[3];
  const float* emb  = (const float*)d_in[4];
  const float* wenc = (const float*)d_in[5];
  const float* wdec = (const float*)d_in[6];
  const float* vw   = (const float*)d_in[7];
  const float* wih0 = (const float*)d_in[8];
  const float* whh0 = (const float*)d_in[9];
  const float* bih0 = (const float*)d_in[10];
  const float* bhh0 = (const float*)d_in[11];
  const float* wih1 = (const float*)d_in[12];
  const float* whh1 = (const float*)d_in[13];
  const float* bih1 = (const float*)d_in[14];
  const float* bhh1 = (const float*)d_in[15];
  const float* fcw  = (const float*)d_in[16];
  const float* fcb  = (const float*)d_in[17];

  char* ws = (char*)d_ws;
  size_t off = 0;
  auto alloc = [&](size_t bytes) {
    char* p = ws + off; off += (bytes + 255) & ~(size_t)255; return p;
  };
  u16*   fcwb    = (u16*)alloc(32768000ULL * 2);
  u16*   encb    = (u16*)alloc(4194304ULL * 2);
  u16*   wencb   = (u16*)alloc(524288ULL * 2);
  u16*   wdecb   = (u16*)alloc(524288ULL * 2);
  u16*   w0cat   = (u16*)alloc(2621440ULL * 2);
  u16*   w1cat   = (u16*)alloc(2097152ULL * 2);
  u16*   embbt   = (u16*)alloc(1048576ULL * 2);
  float* encproj = (float*)alloc(2097152ULL * 4);
  float* bias0   = (float*)alloc(1024ULL * 4);
  float* bias1   = (float*)alloc(1024ULL * 4);
  u16*   ctxst   = (u16*)alloc(2ULL * 32768 * 2);
  u16*   h0st    = (u16*)alloc(2ULL * 32768 * 2);
  u16*   h1st    = (u16*)alloc(2ULL * 32768 * 2);
  u16*   h1all   = (u16*)alloc(2097152ULL * 2);
  u32*   flags   = (u32*)alloc(8192ULL);
  if (off > ws_size) return;  // workspace too small -> visible failure

  float* outlog  = (float*)d_out;                 // [2048][31999]
  float* outattn = outlog + 65533952ULL;          // [32][64][128]

  hipMemsetAsync(flags, 0, 8192, stream);

  prep_kernel<<<2048, 256, 0, stream>>>(
      fcw, enc, wenc, wdec, wih0, whh0, wih1, whh1,
      bih0, bhh0, bih1, bhh1, emb, yin, dih,
      fcwb, encb, wencb, wdecb, w0cat, w1cat, embbt, bias0, bias1,
      h0st, h1st);

  // enc_proj (prescaled): [4096][512] = encb @ wencb^T
  gemm128<<<32 * 4, 256, 0, stream>>>(encb, wencb, nullptr, encproj,
                                      1024, 512, 512, 4);

  (void)hipFuncSetAttribute((const void*)decoder_persistent,
                            hipFuncAttributeMaxDynamicSharedMemorySize, 144896);
  decoder_persistent<<<128, 512, 144896, stream>>>(
      wdecb, w0cat, w1cat, encb, encproj, embbt, bias0, bias1,
      vw, msk, ctxst, h0st, h1st, h1all, outattn, flags);

  // logits: [2048][31999] = h1all[2048][1024] @ fcwb[32000][1024]^T + fc_b
  gemm128<<<16 * 250, 256, 0, stream>>>(h1all, fcwb, fcb, outlog,
                                        1024, 31999, 31999, 250);
}

// Round 6
// 1770.025 us; speedup vs baseline: 2.1643x; 2.1643x over previous
//
#include <hip/hip_runtime.h>

typedef unsigned short u16;
typedef unsigned int u32;
typedef __attribute__((ext_vector_type(8))) short bf16x8;
typedef __attribute__((ext_vector_type(4))) float f32x4;

#define MFMA_BF16(a,b,c) __builtin_amdgcn_mfma_f32_16x16x32_bf16((a),(b),(c),0,0,0)

__device__ __forceinline__ u16 f2bf(float f) {
  union { float f; u32 u; } v; v.f = f;
  u32 r = v.u + 0x7FFFu + ((v.u >> 16) & 1u);
  return (u16)(r >> 16);
}
__device__ __forceinline__ float bf2f(u16 h) {
  union { u32 u; float f; } v; v.u = ((u32)h) << 16; return v.f;
}
__device__ __forceinline__ float tanh_fast(float x) {
  float e = __expf(2.0f * x);
  return 1.0f - 2.0f / (e + 1.0f);
}
__device__ __forceinline__ float exp2_fast(float x) {
  float r; asm("v_exp_f32 %0, %1" : "=v"(r) : "v"(x)); return r;
}
__device__ __forceinline__ float rcp_fast(float x) {
  float r; asm("v_rcp_f32 %0, %1" : "=v"(r) : "v"(x)); return r;
}

// ---- coherent (cross-XCD) ld/st: bypass non-coherent per-XCD L2 ------------
__device__ __forceinline__ void issue_lcoh(bf16x8& v, const u16* p) {
  asm volatile("global_load_dwordx4 %0, %1, off sc0 sc1" : "=v"(v) : "v"(p));
}
__device__ __forceinline__ void issue_lcoh_f4(f32x4& v, const float* p) {
  asm volatile("global_load_dwordx4 %0, %1, off sc0 sc1" : "=v"(v) : "v"(p));
}
__device__ __forceinline__ void issue_lcoh_u32(u32& v, const u32* p) {
  asm volatile("global_load_dword %0, %1, off sc0 sc1" : "=v"(v) : "v"(p));
}
__device__ __forceinline__ void vm_wait0() {
  asm volatile("s_waitcnt vmcnt(0)" ::: "memory");
  __builtin_amdgcn_sched_barrier(0);
}
__device__ __forceinline__ void scoh_f32(float* p, float v) {
  asm volatile("global_store_dword %0, %1, off sc0 sc1" :: "v"(p), "v"(v) : "memory");
}
__device__ __forceinline__ void scoh_u32(u32* p, u32 v) {
  asm volatile("global_store_dword %0, %1, off sc0 sc1" :: "v"(p), "v"(v) : "memory");
}
__device__ __forceinline__ void scoh_u16(u16* p, u16 v) {
  u32 w = v;
  asm volatile("global_store_short %0, %1, off sc0 sc1" :: "v"(p), "v"(w) : "memory");
}
__device__ __forceinline__ u32 poll_load(const u32* p) {
  u32 v;
  asm volatile("global_load_dword %0, %1, off sc0 sc1\n\ts_waitcnt vmcnt(0)"
               : "=v"(v) : "v"(p) : "memory");
  return v;
}

// Poll P per-producer flag slots (128B apart) until all >= target. Wave 0 polls.
__device__ __forceinline__ void poll_flags(const u32* base, int P, u32 target) {
  if ((threadIdx.x >> 6) == 0) {
    const int lane = threadIdx.x & 63;
    if (P == 128) {
      const u32* s0 = base + (size_t)lane * 32;
      const u32* s1 = base + (size_t)(lane + 64) * 32;
      for (;;) {
        u32 v0, v1;
        asm volatile("global_load_dword %0, %2, off sc0 sc1\n\t"
                     "global_load_dword %1, %3, off sc0 sc1\n\t"
                     "s_waitcnt vmcnt(0)"
                     : "=v"(v0), "=v"(v1) : "v"(s0), "v"(s1) : "memory");
        if (__all((v0 >= target) && (v1 >= target))) break;
        __builtin_amdgcn_s_sleep(2);
      }
    } else {
      const u32* s0 = base + (size_t)(lane & (P - 1)) * 32;
      for (;;) {
        u32 v0 = poll_load(s0);
        if (__all(v0 >= target)) break;
        __builtin_amdgcn_s_sleep(2);
      }
    }
  }
  __syncthreads();
  __builtin_amdgcn_sched_barrier(0);
}
// Post own flag after draining coherent data stores.
__device__ __forceinline__ void post_flag(u32* slot, u32 val) {
  asm volatile("s_waitcnt vmcnt(0)" ::: "memory");
  __syncthreads();
  if (threadIdx.x == 0) scoh_u32(slot, val);
}

// ---------------------------------------------------------------------------
// Prep: bf16 conversions, weight re-layout, embedding gather, state init
// ---------------------------------------------------------------------------
__global__ void prep_kernel(
    const float* __restrict__ fcw, const float* __restrict__ enc,
    const float* __restrict__ wenc, const float* __restrict__ wdec,
    const float* __restrict__ wih0, const float* __restrict__ whh0,
    const float* __restrict__ wih1, const float* __restrict__ whh1,
    const float* __restrict__ bih0, const float* __restrict__ bhh0,
    const float* __restrict__ bih1, const float* __restrict__ bhh1,
    const float* __restrict__ emb, const int* __restrict__ yin,
    const float* __restrict__ dih,
    u16* __restrict__ fcwb, u16* __restrict__ encb, u16* __restrict__ wencb,
    u16* __restrict__ wdecb, u16* __restrict__ w0eh, u16* __restrict__ w0ctx,
    u16* __restrict__ w1cat, u16* __restrict__ embbt,
    float* __restrict__ bias0, float* __restrict__ bias1,
    u16* __restrict__ h0buf0, u16* __restrict__ h1buf0)
{
  const float SCL = 2.8853900817779268f;   // 2*log2(e): tanh-arg prescale
  const long long total = 43845632LL;
  for (long long i = (long long)blockIdx.x * 256 + threadIdx.x; i < total;
       i += (long long)gridDim.x * 256) {
    if (i < 32768000LL) {                    // fc_w bf16, padded to 32000 rows
      int r = (int)(i >> 10), c = (int)(i & 1023);
      fcwb[i] = (r < 31999) ? f2bf(fcw[(long long)r * 1024 + c]) : (u16)0;
    } else if (i < 36962304LL) {             // encoder_outputs bf16
      long long j = i - 32768000LL; encb[j] = f2bf(enc[j]);
    } else if (i < 37486592LL) {             // W_enc bf16, prescaled
      long long j = i - 36962304LL; wencb[j] = f2bf(wenc[j] * SCL);
    } else if (i < 38010880LL) {             // W_dec bf16, prescaled
      long long j = i - 37486592LL; wdecb[j] = f2bf(wdec[j] * SCL);
    } else if (i < 39583744LL) {             // w0eh [1024][1536]: [Wih0_emb|Whh0]
      long long j = i - 38010880LL;
      int r = (int)(j / 1536), c = (int)(j % 1536);
      float v = (c < 512) ? wih0[(long long)r * 1536 + c]
                          : whh0[(long long)r * 1024 + (c - 512)];
      w0eh[j] = f2bf(v);
    } else if (i < 40632320LL) {             // w0ctx [1024][1024] = Wih0[:,512:1536]
      long long j = i - 39583744LL;
      int r = (int)(j >> 10), e = (int)(j & 1023);
      w0ctx[j] = f2bf(wih0[(long long)r * 1536 + 512 + e]);
    } else if (i < 42729472LL) {             // w1cat [1024][2048]: [Wih1|Whh1]
      long long j = i - 40632320LL;
      int r = (int)(j >> 11), c = (int)(j & 2047);
      w1cat[j] = f2bf(c < 1024 ? wih1[(r << 10) + c] : whh1[(r << 10) + (c - 1024)]);
    } else if (i < 43778048LL) {             // embedding gather -> bf16 [2048][512]
      long long j = i - 42729472LL;
      int bt = (int)(j >> 9), c = (int)(j & 511);
      int y = yin[bt];
      embbt[j] = f2bf(emb[(long long)y * 512 + c]);
    } else if (i < 43779072LL) {             // bias0 = b_ih0 + b_hh0
      int j = (int)(i - 43778048LL); bias0[j] = bih0[j] + bhh0[j];
    } else if (i < 43780096LL) {             // bias1
      int j = (int)(i - 43779072LL); bias1[j] = bih1[j] + bhh1[j];
    } else if (i < 43812864LL) {             // h0 init [32][1024] -> h0buf[0]
      int j = (int)(i - 43780096LL); h0buf0[j] = f2bf(dih[j]);
    } else {                                 // h1 init [32][1024] -> h1buf[0]
      int j = (int)(i - 43812864LL); h1buf0[j] = f2bf(dih[32768 + j]);
    }
  }
}

// ---------------------------------------------------------------------------
// Generic 128x128-tile bf16 MFMA GEMM:  C[M][N] = A[M][K] * B[N][K]^T + bias
// OUT16=1 -> bf16 output, OUT16=0 -> f32 output.
// ---------------------------------------------------------------------------
template <int OUT16>
__global__ __launch_bounds__(256) void gemm128(
    const u16* __restrict__ A, const u16* __restrict__ Bm,
    const float* __restrict__ bias, void* __restrict__ Cv,
    int K, int ldc, int Nvalid, int ntN)
{
  __shared__ u16 As[128 * 32];
  __shared__ u16 Bs[128 * 32];
  const int tid = threadIdx.x;
  const int bid = blockIdx.x;
  const int tM = bid / ntN, tN = bid - tM * ntN;
  const int m0 = tM * 128, n0 = tN * 128;
  const int lane = tid & 63, wid = tid >> 6;
  const int wm = wid >> 1, wn = wid & 1;
  const int srow = tid >> 1, scol = (tid & 1) * 16;

  const u16* gA = A + (size_t)(m0 + srow) * K + scol;
  const u16* gB = Bm + (size_t)(n0 + srow) * K + scol;
  u16* sA = &As[srow * 32 + scol];
  u16* sB = &Bs[srow * 32 + scol];

  f32x4 acc[4][4];
#pragma unroll
  for (int i = 0; i < 4; ++i)
#pragma unroll
    for (int j = 0; j < 4; ++j) acc[i][j] = (f32x4){0, 0, 0, 0};

  const int aoff = (wm * 64 + (lane & 15)) * 32 + ((lane >> 4) << 3);
  const int boff = (wn * 64 + (lane & 15)) * 32 + ((lane >> 4) << 3);

  for (int k0 = 0; k0 < K; k0 += 32) {
    bf16x8 va0 = *(const bf16x8*)(gA + k0);
    bf16x8 va1 = *(const bf16x8*)(gA + k0 + 8);
    bf16x8 vb0 = *(const bf16x8*)(gB + k0);
    bf16x8 vb1 = *(const bf16x8*)(gB + k0 + 8);
    __syncthreads();
    *((bf16x8*)sA) = va0;  *((bf16x8*)(sA + 8)) = va1;
    *((bf16x8*)sB) = vb0;  *((bf16x8*)(sB + 8)) = vb1;
    __syncthreads();
    bf16x8 af[4], bfj[4];
#pragma unroll
    for (int i = 0; i < 4; ++i) af[i] = *(const bf16x8*)&As[aoff + i * 512];
#pragma unroll
    for (int j = 0; j < 4; ++j) bfj[j] = *(const bf16x8*)&Bs[boff + j * 512];
#pragma unroll
    for (int i = 0; i < 4; ++i)
#pragma unroll
      for (int j = 0; j < 4; ++j)
        acc[i][j] = MFMA_BF16(af[i], bfj[j], acc[i][j]);
  }

#pragma unroll
  for (int i = 0; i < 4; ++i) {
#pragma unroll
    for (int j = 0; j < 4; ++j) {
      int row = m0 + wm * 64 + i * 16 + ((lane >> 4) << 2);
      int cc = n0 + wn * 64 + j * 16 + (lane & 15);
      if (cc < Nvalid) {
        float bs = bias ? bias[cc] : 0.f;
#pragma unroll
        for (int jj = 0; jj < 4; ++jj) {
          if (OUT16)
            ((u16*)Cv)[(size_t)(row + jj) * ldc + cc] = f2bf(acc[i][j][jj] + bs);
          else
            ((float*)Cv)[(size_t)(row + jj) * ldc + cc] = acc[i][j][jj] + bs;
        }
      }
    }
  }
}

// ---------------------------------------------------------------------------
// Persistent recurrence. Grid = 224 x 512, 1 block/CU.
// Roles: [0,64) H1+decpPartials | [64,96) SCORE | [96,224) H0
// Chain per step: H1 -> SCORE -> H0 -> H1 (3 handoffs, per-producer flags).
// All per-step weights LDS-resident; only state crosses blocks (sc0sc1).
// ---------------------------------------------------------------------------
__global__ __launch_bounds__(512, 1) void decoder_persistent(
    const u16* __restrict__ wdecb, const u16* __restrict__ w0eh,
    const u16* __restrict__ w1cat, const u16* __restrict__ encprojb,
    const u16* __restrict__ encW0T, const u16* __restrict__ embbt,
    const float* __restrict__ bias0, const float* __restrict__ bias1,
    const float* __restrict__ vw, const int* __restrict__ msk,
    u16* __restrict__ partials, float* __restrict__ attbuf,
    u16* __restrict__ h0buf, u16* __restrict__ h1buf,
    u16* __restrict__ h1all, float* __restrict__ outattn, u32* flags)
{
  extern __shared__ char smem[];
  const int tid = threadIdx.x;
  const int bid = blockIdx.x;
  const int lane = tid & 63, wid = tid >> 6;
  const f32x4 zero4 = {0, 0, 0, 0};

  if (bid < 64) {
    // ============ H1: h1 = tanh([h0|h1prev] @ W1^T + b1); decp partials =====
    const int hh = bid, n0 = hh * 16;
    u16* w1L = (u16*)smem;                   // [16][2048]      65536 B
    u16* wdL = (u16*)(smem + 65536);         // [512][32]       32768 B (k16..31 = 0)
    u16* h1newL = (u16*)(smem + 98304);      // [32][32]        2048 B (k16..31 = 0)
    float* scr = (float*)(smem + 100352);    // [16][64][4]     16384 B
    float* b1L = (float*)(smem + 116736);    // [16]
    {
      for (int c = tid; c < 4096; c += 512)
        *(bf16x8*)&w1L[c * 8] = *(const bf16x8*)&w1cat[(size_t)n0 * 2048 + c * 8];
      bf16x8 r0 = *(const bf16x8*)&wdecb[(size_t)tid * 1024 + n0];
      bf16x8 r1 = *(const bf16x8*)&wdecb[(size_t)tid * 1024 + n0 + 8];
      bf16x8 z = {0, 0, 0, 0, 0, 0, 0, 0};
      *(bf16x8*)&wdL[tid * 32] = r0;
      *(bf16x8*)&wdL[tid * 32 + 8] = r1;
      *(bf16x8*)&wdL[tid * 32 + 16] = z;
      *(bf16x8*)&wdL[tid * 32 + 24] = z;
      h1newL[tid] = 0; h1newL[512 + tid] = 0;
      if (tid < 16) b1L[tid] = bias1[n0 + tid];
    }
    __syncthreads();
    { // h1newL <- h1 init (plain: prep output)
      int b = tid >> 4, n = tid & 15;
      h1newL[b * 32 + n] = h1buf[(size_t)b * 1024 + n0 + n];
    }
    __syncthreads();

    for (int t = -1; t < 64; ++t) {
      if (t >= 0) {
        poll_flags(flags, 64, (u32)(t + 1));               // peers wrote h1buf[t&1]
        const u16* hp = h1buf + (size_t)(t & 1) * 32768;
        f32x4 acc[2] = {zero4, zero4};
        {   // early: h1prev (k 1024..2047)
          bf16x8 av[8];
#pragma unroll
          for (int mt = 0; mt < 2; ++mt)
#pragma unroll
            for (int i = 0; i < 4; ++i) {
              int b = mt * 16 + (lane & 15);
              int k = (wid * 4 + i) * 32 + ((lane >> 4) << 3);
              issue_lcoh(av[mt * 4 + i], hp + (size_t)b * 1024 + k);
            }
          vm_wait0();
#pragma unroll
          for (int mt = 0; mt < 2; ++mt)
#pragma unroll
            for (int i = 0; i < 4; ++i) {
              int n = lane & 15;
              int k = (wid * 4 + i) * 32 + ((lane >> 4) << 3);
              acc[mt] = MFMA_BF16(av[mt * 4 + i],
                                  *(const bf16x8*)&w1L[n * 2048 + 1024 + k], acc[mt]);
            }
        }
        poll_flags(flags + 96 * 32, 128, (u32)(t + 1));    // h0(t) ready
        const u16* hn = h0buf + (size_t)((t + 1) & 1) * 32768;
        {   // late: h0 new (k 0..1023)
          bf16x8 av[8];
#pragma unroll
          for (int mt = 0; mt < 2; ++mt)
#pragma unroll
            for (int i = 0; i < 4; ++i) {
              int b = mt * 16 + (lane & 15);
              int k = (wid * 4 + i) * 32 + ((lane >> 4) << 3);
              issue_lcoh(av[mt * 4 + i], hn + (size_t)b * 1024 + k);
            }
          vm_wait0();
#pragma unroll
          for (int mt = 0; mt < 2; ++mt)
#pragma unroll
            for (int i = 0; i < 4; ++i) {
              int n = lane & 15;
              int k = (wid * 4 + i) * 32 + ((lane >> 4) << 3);
              acc[mt] = MFMA_BF16(av[mt * 4 + i],
                                  *(const bf16x8*)&w1L[n * 2048 + k], acc[mt]);
            }
        }
        *(f32x4*)&scr[((wid * 2 + 0) * 64 + lane) * 4] = acc[0];
        *(f32x4*)&scr[((wid * 2 + 1) * 64 + lane) * 4] = acc[1];
        __syncthreads();
        {   // combine + tanh + stores
          int b = tid >> 4, n = tid & 15;
          int lanep = ((b & 15) >> 2) * 16 + n, r = b & 3, mt = b >> 4;
          float s = b1L[n];
#pragma unroll
          for (int w = 0; w < 8; ++w) s += scr[((w * 2 + mt) * 64 + lanep) * 4 + r];
          u16 v = f2bf(tanh_fast(s));
          h1newL[b * 32 + n] = v;
          scoh_u16(h1buf + (size_t)((t + 1) & 1) * 32768 + (size_t)b * 1024 + n0 + n, v);
          h1all[(size_t)(b * 64 + t) * 1024 + n0 + n] = v;   // plain (next kernel)
        }
        __syncthreads();
      }
      {   // decp partials: [32 b][512 a] slice from this block's 16 k-cols
#pragma unroll
        for (int mt = 0; mt < 2; ++mt) {
          bf16x8 a = *(const bf16x8*)&h1newL[(mt * 16 + (lane & 15)) * 32 + ((lane >> 4) << 3)];
#pragma unroll
          for (int i = 0; i < 4; ++i) {
            int nt = wid * 4 + i;
            bf16x8 bb = *(const bf16x8*)&wdL[(nt * 16 + (lane & 15)) * 32 + ((lane >> 4) << 3)];
            f32x4 c = MFMA_BF16(a, bb, zero4);
            int a0 = nt * 16 + (lane & 15);
#pragma unroll
            for (int j = 0; j < 4; ++j) {
              int b = mt * 16 + ((lane >> 4) << 2) + j;
              scoh_u16(partials + ((size_t)b * 64 + hh) * 512 + a0, f2bf(c[j]));
            }
          }
        }
      }
      post_flag(flags + (size_t)hh * 32, (u32)(t + 2));
    }
  } else if (bid < 96) {
    // ============ SCORE: decp reduce + tanh scores + softmax -> att ==========
    const int b = bid - 64;
    u16* epL = (u16*)smem;                   // [128][520]      133120 B
    float* vwL = (float*)(smem + 133120);    // [512]
    float* decp2 = (float*)(smem + 135168);  // [2][512]
    float* decpL = (float*)(smem + 139264);  // [512]
    float* eL = (float*)(smem + 141312);     // [128]
    float* mkL = (float*)(smem + 141824);    // [128]
    float* sumL = (float*)(smem + 142336);   // [8]
    {
      for (int c = tid; c < 8192; c += 512)
        *(bf16x8*)&epL[(c >> 6) * 520 + (c & 63) * 8] =
            *(const bf16x8*)&encprojb[((size_t)b * 128 + (c >> 6)) * 512 + (c & 63) * 8];
      vwL[tid] = vw[tid];
      if (tid < 128) mkL[tid] = (float)msk[b * 128 + tid];
    }
    __syncthreads();
    for (int t = 0; t < 64; ++t) {
      poll_flags(flags, 64, (u32)(t + 1));
      {   // reduce 64 partials -> decp
        const int a2 = tid & 255, ph = tid >> 8;
        const u32* pb = (const u32*)partials + (size_t)b * 16384 + (size_t)ph * 32 * 256 + a2;
        float acc0 = 0.f, acc1 = 0.f;
        u32 wv[16];
#pragma unroll
        for (int g = 0; g < 2; ++g) {
#pragma unroll
          for (int i = 0; i < 16; ++i)
            issue_lcoh_u32(wv[i], pb + (size_t)(g * 16 + i) * 256);
          vm_wait0();
#pragma unroll
          for (int i = 0; i < 16; ++i) {
            acc0 += bf2f((u16)(wv[i] & 0xffffu));
            acc1 += bf2f((u16)(wv[i] >> 16));
          }
        }
        decp2[ph * 512 + a2 * 2] = acc0;
        decp2[ph * 512 + a2 * 2 + 1] = acc1;
      }
      __syncthreads();
      decpL[tid] = decp2[tid] + decp2[512 + tid];
      __syncthreads();
      {   // scores
        const int s = tid >> 2, q = tid & 3;
        const u16* ep = &epL[s * 520 + q * 128];
        const float* dp = &decpL[q * 128];
        const float* vv = &vwL[q * 128];
        float a0 = 0.f, a1 = 0.f;
#pragma unroll
        for (int ii = 0; ii < 16; ++ii) {
          int i = (ii + q * 4) & 15;
          bf16x8 ev = *(const bf16x8*)(ep + i * 8);
#pragma unroll
          for (int e = 0; e < 8; e += 2) {
            float x0 = bf2f((u16)ev[e]) + dp[i * 8 + e];          // prescaled
            float x1 = bf2f((u16)ev[e + 1]) + dp[i * 8 + e + 1];
            a0 = fmaf(vv[i * 8 + e],     1.f - 2.f * rcp_fast(exp2_fast(x0) + 1.f), a0);
            a1 = fmaf(vv[i * 8 + e + 1], 1.f - 2.f * rcp_fast(exp2_fast(x1) + 1.f), a1);
          }
        }
        float acc = a0 + a1;
        acc += __shfl_xor(acc, 1);
        acc += __shfl_xor(acc, 2);
        float e = 0.f;
        if (q == 0) { e = (mkL[s] != 0.f) ? __expf(acc) : 0.f; eL[s] = e; }
        float ee = e;
#pragma unroll
        for (int off = 1; off < 64; off <<= 1) ee += __shfl_xor(ee, off);
        if (lane == 0) sumL[wid] = ee;
      }
      __syncthreads();
      {
        float tot = sumL[0] + sumL[1] + sumL[2] + sumL[3] +
                    sumL[4] + sumL[5] + sumL[6] + sumL[7];
        if (tid < 128) {
          float att = (tot > 0.f) ? eL[tid] * rcp_fast(tot) : 0.0078125f;
          outattn[(size_t)(b * 64 + t) * 128 + tid] = att;
          scoh_f32(attbuf + b * 128 + tid, att);
        }
      }
      post_flag(flags + (size_t)bid * 32, (u32)(t + 1));
    }
  } else {
    // ============ H0: h0 = tanh(emb·W + h0prev·W + att·encW0 + b0) ==========
    const int h = bid - 96, j0 = h * 8;
    u16* w0L = (u16*)smem;                   // [16][1536] rows 8..15 unused   49152 B
    u16* e0L = (u16*)(smem + 49152);         // j*4360 + b*136 + s             69760 B
    float* attL = (float*)(smem + 118912);   // [32][128]                      16384 B
    float* scrH = (float*)(smem + 135296);   // [16][64][4]                    16384 B
    float* attP = (float*)(smem + 151680);   // [32][8]                        1024 B
    float* b0L = (float*)(smem + 152704);    // [8]
    {
      for (int c = tid; c < 1536; c += 512) {   // w0L rows 0..7
        int j = c / 192, off = (c % 192) * 8;
        *(bf16x8*)&w0L[j * 1536 + off] = *(const bf16x8*)&w0eh[(size_t)(j0 + j) * 1536 + off];
      }
      for (int c = tid; c < 4096; c += 512) {   // e0L
        int j = c >> 9, rem = c & 511, bb = rem >> 4, so = (rem & 15) * 8;
        *(bf16x8*)&e0L[j * 4360 + bb * 136 + so] =
            *(const bf16x8*)&encW0T[(size_t)(j0 + j) * 4096 + bb * 128 + so];
      }
      if (tid < 8) b0L[tid] = bias0[j0 + tid];
    }
    __syncthreads();
    for (int t = 0; t < 64; ++t) {
      poll_flags(flags + 96 * 32, 128, (u32)t);        // h0prev complete (peers)
      f32x4 acc[2] = {zero4, zero4};
      {   // emb (plain) + h0prev (coherent) MFMA, K-split across waves
        bf16x8 ave[4], avh[8];
#pragma unroll
        for (int mt = 0; mt < 2; ++mt)
#pragma unroll
          for (int i = 0; i < 2; ++i) {
            int b = mt * 16 + (lane & 15);
            int k = (wid * 2 + i) * 32 + ((lane >> 4) << 3);
            ave[mt * 2 + i] = *(const bf16x8*)&embbt[((size_t)b * 64 + t) * 512 + k];
          }
        const u16* hp = h0buf + (size_t)(t & 1) * 32768;
#pragma unroll
        for (int mt = 0; mt < 2; ++mt)
#pragma unroll
          for (int i = 0; i < 4; ++i) {
            int b = mt * 16 + (lane & 15);
            int k = (wid * 4 + i) * 32 + ((lane >> 4) << 3);
            issue_lcoh(avh[mt * 4 + i], hp + (size_t)b * 1024 + k);
          }
        vm_wait0();
#pragma unroll
        for (int mt = 0; mt < 2; ++mt) {
#pragma unroll
          for (int i = 0; i < 2; ++i) {
            int n = lane & 15;
            int k = (wid * 2 + i) * 32 + ((lane >> 4) << 3);
            acc[mt] = MFMA_BF16(ave[mt * 2 + i], *(const bf16x8*)&w0L[n * 1536 + k], acc[mt]);
          }
#pragma unroll
          for (int i = 0; i < 4; ++i) {
            int n = lane & 15;
            int k = (wid * 4 + i) * 32 + ((lane >> 4) << 3);
            acc[mt] = MFMA_BF16(avh[mt * 4 + i],
                                *(const bf16x8*)&w0L[n * 1536 + 512 + k], acc[mt]);
          }
        }
        *(f32x4*)&scrH[((wid * 2 + 0) * 64 + lane) * 4] = acc[0];
        *(f32x4*)&scrH[((wid * 2 + 1) * 64 + lane) * 4] = acc[1];
      }
      poll_flags(flags + 64 * 32, 32, (u32)(t + 1));   // att(t) ready
      {
        f32x4 v0, v1;
        issue_lcoh_f4(v0, attbuf + tid * 8);
        issue_lcoh_f4(v1, attbuf + tid * 8 + 4);
        vm_wait0();
        *(f32x4*)&attL[tid * 8] = v0;
        *(f32x4*)&attL[tid * 8 + 4] = v1;
      }
      __syncthreads();
      {   // att-part: thread (b, j, h2)
        int b = tid >> 4, j = (tid >> 1) & 7, h2 = tid & 1;
        const u16* ep = &e0L[j * 4360 + b * 136 + h2 * 64];
        const float* ar = &attL[b * 128 + h2 * 64];
        float a2 = 0.f;
#pragma unroll
        for (int c8 = 0; c8 < 8; ++c8) {
          bf16x8 ev = *(const bf16x8*)(ep + c8 * 8);
#pragma unroll
          for (int e = 0; e < 8; ++e) a2 = fmaf(ar[c8 * 8 + e], bf2f((u16)ev[e]), a2);
        }
        a2 += __shfl_xor(a2, 1);
        if (h2 == 0) attP[b * 8 + j] = a2;
      }
      __syncthreads();
      if (tid < 256) {
        int b = tid >> 3, j = tid & 7;
        int lanep = ((b & 15) >> 2) * 16 + j, r = b & 3, mt = b >> 4;
        float s = attP[b * 8 + j] + b0L[j];
#pragma unroll
        for (int w = 0; w < 8; ++w) s += scrH[((w * 2 + mt) * 64 + lanep) * 4 + r];
        u16 v = f2bf(tanh_fast(s));
        scoh_u16(h0buf + (size_t)((t + 1) & 1) * 32768 + (size_t)b * 1024 + j0 + j, v);
      }
      post_flag(flags + (size_t)bid * 32, (u32)(t + 1));
    }
  }
}

// ---------------------------------------------------------------------------
extern "C" void kernel_launch(void* const* d_in, const int* in_sizes, int n_in,
                              void* d_out, int out_size, void* d_ws, size_t ws_size,
                              hipStream_t stream)
{
  const int*   yin  = (const int*)d_in[0];
  const float* enc  = (const float*)d_in[1];
  const float* dih  = (const float*)d_in[2];
  const int*   msk  = (const int*)d_in[3];
  const float* emb  = (const float*)d_in[4];
  const float* wenc = (const float*)d_in[5];
  const float* wdec = (const float*)d_in[6];
  const float* vw   = (const float*)d_in[7];
  const float* wih0 = (const float*)d_in[8];
  const float* whh0 = (const float*)d_in[9];
  const float* bih0 = (const float*)d_in[10];
  const float* bhh0 = (const float*)d_in[11];
  const float* wih1 = (const float*)d_in[12];
  const float* whh1 = (const float*)d_in[13];
  const float* bih1 = (const float*)d_in[14];
  const float* bhh1 = (const float*)d_in[15];
  const float* fcw  = (const float*)d_in[16];
  const float* fcb  = (const float*)d_in[17];

  char* ws = (char*)d_ws;
  size_t off = 0;
  auto alloc = [&](size_t bytes) {
    char* p = ws + off; off += (bytes + 255) & ~(size_t)255; return p;
  };
  u16*   fcwb     = (u16*)alloc(32768000ULL * 2);
  u16*   encb     = (u16*)alloc(4194304ULL * 2);
  u16*   wencb    = (u16*)alloc(524288ULL * 2);
  u16*   wdecb    = (u16*)alloc(524288ULL * 2);
  u16*   w0eh     = (u16*)alloc(1572864ULL * 2);
  u16*   w0ctx    = (u16*)alloc(1048576ULL * 2);
  u16*   w1cat    = (u16*)alloc(2097152ULL * 2);
  u16*   embbt    = (u16*)alloc(1048576ULL * 2);
  u16*   encprojb = (u16*)alloc(2097152ULL * 2);
  u16*   encW0T   = (u16*)alloc(4194304ULL * 2);
  u16*   partials = (u16*)alloc(1048576ULL * 2);
  float* attbuf   = (float*)alloc(4096ULL * 4);
  u16*   h0buf    = (u16*)alloc(65536ULL * 2);
  u16*   h1buf    = (u16*)alloc(65536ULL * 2);
  u16*   h1all    = (u16*)alloc(2097152ULL * 2);
  float* bias0    = (float*)alloc(1024ULL * 4);
  float* bias1    = (float*)alloc(1024ULL * 4);
  u32*   flags    = (u32*)alloc(32768ULL);
  if (off > ws_size) return;  // workspace too small -> visible failure

  float* outlog  = (float*)d_out;                 // [2048][31999]
  float* outattn = outlog + 65533952ULL;          // [32][64][128]

  (void)hipMemsetAsync(flags, 0, 32768, stream);

  prep_kernel<<<2048, 256, 0, stream>>>(
      fcw, enc, wenc, wdec, wih0, whh0, wih1, whh1,
      bih0, bhh0, bih1, bhh1, emb, yin, dih,
      fcwb, encb, wencb, wdecb, w0eh, w0ctx, w1cat, embbt, bias0, bias1,
      h0buf, h1buf);

  // enc_proj (prescaled, bf16): [4096][512] = encb @ wencb^T
  gemm128<1><<<32 * 4, 256, 0, stream>>>(encb, wencb, nullptr, encprojb,
                                         1024, 512, 512, 4);
  // encW0T (bf16): [1024 j][4096 bs] = w0ctx @ encb^T
  gemm128<1><<<8 * 32, 256, 0, stream>>>(w0ctx, encb, nullptr, encW0T,
                                         1024, 4096, 4096, 32);

  (void)hipFuncSetAttribute((const void*)decoder_persistent,
                            hipFuncAttributeMaxDynamicSharedMemorySize, 153600);
  decoder_persistent<<<224, 512, 153600, stream>>>(
      wdecb, w0eh, w1cat, encprojb, encW0T, embbt, bias0, bias1,
      vw, msk, partials, attbuf, h0buf, h1buf, h1all, outattn, flags);

  // logits: [2048][31999] = h1all @ fcwb^T + fc_b
  gemm128<0><<<16 * 250, 256, 0, stream>>>(h1all, fcwb, fcb, outlog,
                                           1024, 31999, 31999, 250);
}